// Round 11
// baseline (265.183 us; speedup 1.0000x reference)
//
#include <hip/hip_runtime.h>
#include <hip/hip_bf16.h>
#include <stdint.h>

#define NB 2
#define SEQ 1024
#define DMODEL 768
#define NH 12
#define DH 64
#define SCALE 0.125f
#define NCHE 4         // attn_exp col chunks (256 cols each)
#define NCHM 8         // attn_main col chunks (128 cols each)

typedef __hip_bfloat16 bf16;
typedef __attribute__((ext_vector_type(8))) short short8;   // 8 x bf16 = 4 VGPRs
typedef __attribute__((ext_vector_type(4))) float f32x4;    // MFMA C/D

__device__ __forceinline__ bf16 f2b(float x){ return __float2bfloat16(x); }
__device__ __forceinline__ short f2bs(float x){
  bf16 h = __float2bfloat16(x); return *reinterpret_cast<short*>(&h);
}
__device__ __forceinline__ float s2f(short u){
  return __uint_as_float(((unsigned)(unsigned short)u) << 16);
}

// async global->LDS 16B: LDS dest wave-uniform base; HW adds lane*16.
__device__ __forceinline__ void gl_lds16(const bf16* g, bf16* l){
  __builtin_amdgcn_global_load_lds(
      (const __attribute__((address_space(1))) void*)g,
      (__attribute__((address_space(3))) void*)l, 16, 0, 0);
}

// ---------------- merged prelude: LN rows | weight cvt | M + lsum zero ----------------
// grid: [0,2048) LN, [2048, 2048+9216) cvt, [11264, 11264+97) prep
__global__ __launch_bounds__(256) void prep_all(const float* __restrict__ x,
                                                const float* __restrict__ g,
                                                const float* __restrict__ bta,
                                                const float* __restrict__ w1, int n1,
                                                const float* __restrict__ w2, int n2,
                                                const float* __restrict__ theta,
                                                const float* __restrict__ gnn,
                                                bf16* __restrict__ xn,
                                                bf16* __restrict__ wb,
                                                float* __restrict__ Mm,
                                                float* __restrict__ l){
  int bx = blockIdx.x, t = threadIdx.x;
  if (bx < 2048){
    const float* xr = x + (size_t)bx*DMODEL;
    float v0[3]; float s = 0.f, s2 = 0.f;
    #pragma unroll
    for (int i=0;i<3;i++){ float val = xr[t+256*i]; v0[i]=val; s+=val; s2+=val*val; }
    __shared__ float sb[256], s2b[256];
    sb[t]=s; s2b[t]=s2; __syncthreads();
    for (int off=128; off>0; off>>=1){
      if (t<off){ sb[t]+=sb[t+off]; s2b[t]+=s2b[t+off]; }
      __syncthreads();
    }
    float mean = sb[0]*(1.f/DMODEL);
    float var  = s2b[0]*(1.f/DMODEL) - mean*mean;
    float rstd = rsqrtf(var + 1e-5f);
    #pragma unroll
    for (int i=0;i<3;i++){
      int c = t+256*i;
      xn[(size_t)bx*DMODEL + c] = f2b((v0[i]-mean)*rstd*g[c] + bta[c]);
    }
  } else if (bx < 2048+9216){
    int i = (bx-2048)*256 + t;
    if (i < n1) wb[i] = f2b(w1[i]);
    else if (i < n1+n2) wb[i] = f2b(w2[i-n1]);
  } else {
    int sub = bx - (2048+9216);
    if (sub == 0){
      if (t < 144){
        int i = t/12, kx = t%12;
        float sacc = 0.f;
        for (int j=0;j<12;j++) sacc += (-0.5f)*theta[i*12+j] * gnn[j*12+kx];
        Mm[t] = sacc;
      }
    } else {
      l[(sub-1)*256 + t] = 0.f;    // 96*256 = 24576 = 2*12*1024
    }
  }
}

// ---------------- QKV GEMM (MFMA): xn[2048,768] @ wqkv^T -> q,k bf16 [b,h,n,d]; v -> vt [b,h,d,n] ----------------
__global__ __launch_bounds__(256) void gemm_qkv(const bf16* __restrict__ A,
                                                const bf16* __restrict__ W,
                                                bf16* __restrict__ q,
                                                bf16* __restrict__ k,
                                                bf16* __restrict__ vt){
  __shared__ bf16 As[128*32];
  __shared__ bf16 Bs[128*32];
  int n0 = blockIdx.x*128, m0 = blockIdx.y*128;
  int t = threadIdx.x, w = t>>6, lane = t&63;
  int ln16 = lane&15, q8 = (lane>>4)*8;
  int wm = w>>1, wn = w&1;
  f32x4 acc[4][4] = {};
  for (int k0=0; k0<768; k0+=32){
    __syncthreads();
    #pragma unroll
    for (int i=0;i<2;i++){
      int cc = t + i*256;
      int r = cc>>2, ko = (cc&3)*8;
      gl_lds16(&A[(size_t)(m0+r)*768 + k0+ko], &As[(size_t)(w*64 + i*256)*8]);
      gl_lds16(&W[(size_t)(n0+r)*768 + k0+ko], &Bs[(size_t)(w*64 + i*256)*8]);
    }
    __syncthreads();
    short8 af[4], bfr[4];
    #pragma unroll
    for (int mi=0;mi<4;mi++) af[mi]  = *(const short8*)&As[(wm*64+mi*16+ln16)*32 + q8];
    #pragma unroll
    for (int ni=0;ni<4;ni++) bfr[ni] = *(const short8*)&Bs[(wn*64+ni*16+ln16)*32 + q8];
    #pragma unroll
    for (int mi=0;mi<4;mi++)
      #pragma unroll
      for (int ni=0;ni<4;ni++)
        acc[mi][ni] = __builtin_amdgcn_mfma_f32_16x16x32_bf16(af[mi], bfr[ni], acc[mi][ni], 0, 0, 0);
  }
  int quad4 = (lane>>4)*4;
  #pragma unroll
  for (int mi=0;mi<4;mi++){
    #pragma unroll
    for (int ni=0;ni<4;ni++){
      int cg = n0 + wn*64 + ni*16 + ln16;
      int which = cg/768; int rem = cg - which*768;
      int h = rem>>6, dd = rem&63;
      #pragma unroll
      for (int r=0;r<4;r++){
        int m = m0 + wm*64 + mi*16 + quad4 + r;
        int bb = m>>10, n = m&1023;
        float val = acc[mi][ni][r];
        if (which==0)      q [((size_t)(bb*NH+h)*SEQ + n)*DH + dd] = f2b(val*SCALE);
        else if (which==1) k [((size_t)(bb*NH+h)*SEQ + n)*DH + dd] = f2b(val);
        else               vt[((size_t)(bb*NH+h)*DH + dd)*SEQ + n] = f2b(val);
      }
    }
  }
}

// ---------------- attn_exp: QK^T -> exp (bf16, UNNORMALIZED) to global + l partials ----------------
// grid (64 strips, NCHE, NB*3 headgroups); 256 thr = 4 waves, wave = one head. No LDS/barriers.
__global__ __launch_bounds__(256) void attn_exp(const bf16* __restrict__ q,
                                                const bf16* __restrict__ k,
                                                float* __restrict__ l,
                                                bf16* __restrict__ eg){
  int strip = blockIdx.x, ch = blockIdx.y;
  int b = blockIdx.z/3, hg = blockIdx.z%3;
  int t = threadIdx.x; int h = hg*4 + (t>>6); int lane = t&63;
  int ln16 = lane&15, quad = lane>>4; int q8 = quad*8, quad4 = quad*4;
  int r0 = strip*16;
  const bf16* qrow = q + ((size_t)(b*NH+h)*SEQ + r0 + ln16)*DH;
  short8 aq0 = *(const short8*)(qrow + q8);
  short8 aq1 = *(const short8*)(qrow + 32 + q8);
  const bf16* kB = k + ((size_t)(b*NH+h)*SEQ)*DH;
  bf16* egh = eg + (((size_t)(b*NH+h))<<20);
  float ls[4] = {0.f,0.f,0.f,0.f};
  #pragma unroll 4
  for (int i=0;i<16;i++){
    int c0 = ch*256 + i*16;
    const bf16* krow = kB + (size_t)(c0 + ln16)*DH;
    short8 bk0 = *(const short8*)(krow + q8);
    short8 bk1 = *(const short8*)(krow + 32 + q8);
    f32x4 a = {0.f,0.f,0.f,0.f};
    a = __builtin_amdgcn_mfma_f32_16x16x32_bf16(aq0, bk0, a, 0, 0, 0);
    a = __builtin_amdgcn_mfma_f32_16x16x32_bf16(aq1, bk1, a, 0, 0, 0);
    #pragma unroll
    for (int r=0;r<4;r++){
      float e = __expf(a[r]);
      ls[r] += e;
      egh[(size_t)(r0+quad4+r)*1024 + c0 + ln16] = f2b(e);
    }
  }
  #pragma unroll
  for (int msk=1; msk<16; msk<<=1){
    #pragma unroll
    for (int r=0;r<4;r++) ls[r] += __shfl_xor(ls[r], msk);
  }
  if (ln16 == 0){
    #pragma unroll
    for (int r=0;r<4;r++)
      atomicAdd(&l[((size_t)(b*NH+h))*SEQ + r0 + quad4 + r], ls[r]);
  }
}

// ---------------- attn_main: stream exp -> normalized mix -> PV partial. NO LDS, NO BARRIERS ----------------
// grid (64 strips, NCHM, NB); 768 thr = 12 waves, wave h = head h. Normalization folded
// into M' = M[h][j]/l_j[qrow] (once per wave). 12 waves of a block read the same exp
// tiles -> L1 reuse.
__global__ __launch_bounds__(768) void attn_main(const bf16* __restrict__ eg,
                                                 const bf16* __restrict__ vt,
                                                 const float* __restrict__ Mm,
                                                 const float* __restrict__ l,
                                                 float* __restrict__ opart){
  int strip = blockIdx.x, ch = blockIdx.y, b = blockIdx.z;
  int t = threadIdx.x; int h = t>>6; int lane = t&63;
  int ln16 = lane&15, quad = lane>>4; int q8 = quad*8, quad4 = quad*4;
  int r0 = strip*16;
  const bf16* vB  = vt + ((size_t)(b*NH+h)*DH)*SEQ;
  const bf16* egb = eg + (((size_t)b*NH)<<20);
  const size_t rowoff = (size_t)(r0 + ln16)*1024;

  float Mp[12];
  #pragma unroll
  for (int j=0;j<12;j++){
    float lj = l[((size_t)(b*NH+j))*SEQ + r0 + ln16];
    Mp[j] = Mm[h*12+j] / lj;
  }
  float ihl = 1.0f / l[((size_t)(b*NH+h))*SEQ + r0 + ln16];

  f32x4 oacc[4] = {};
  for (int it=0; it<4; it++){
    int c0 = ch*128 + it*32;
    float sm[8] = {0.f,0.f,0.f,0.f,0.f,0.f,0.f,0.f};
    #pragma unroll
    for (int j=0;j<12;j++){
      short8 u = *(const short8*)&egb[(((size_t)j)<<20) + rowoff + c0 + q8];
      float m = Mp[j];
      #pragma unroll
      for (int e=0;e<8;e++) sm[e] += m*s2f(u[e]);
    }
    short8 uh = *(const short8*)&egb[(((size_t)h)<<20) + rowoff + c0 + q8];
    short8 afrag;
    #pragma unroll
    for (int e=0;e<8;e++) afrag[e] = f2bs(s2f(uh[e])*ihl + fmaxf(sm[e], 0.f));
    #pragma unroll
    for (int ni=0; ni<4; ni++){
      short8 bv = *(const short8*)&vB[(size_t)(ni*16 + ln16)*SEQ + c0 + q8];
      oacc[ni] = __builtin_amdgcn_mfma_f32_16x16x32_bf16(afrag, bv, oacc[ni], 0, 0, 0);
    }
  }
  float* dst = opart + ((size_t)ch*NB*SEQ + (size_t)b*SEQ)*DMODEL;
  #pragma unroll
  for (int ni=0; ni<4; ni++)
    #pragma unroll
    for (int r=0; r<4; r++){
      int n = r0 + quad4 + r;
      dst[(size_t)n*DMODEL + h*DH + ni*16 + ln16] = oacc[ni][r];
    }
}

// ---------------- reduce partials: aout = bf16( sum_ch opart ) ----------------
__global__ __launch_bounds__(256) void reduce_kernel(const float* __restrict__ opart,
                                                     bf16* __restrict__ aout){
  const size_t TOT = (size_t)NB*SEQ*DMODEL;      // 1,572,864
  size_t i = ((size_t)blockIdx.x*256 + threadIdx.x)*4;
  float4 s = *(const float4*)&opart[i];
  #pragma unroll
  for (int c=1;c<NCHM;c++){
    float4 p = *(const float4*)&opart[c*TOT + i];
    s.x += p.x; s.y += p.y; s.z += p.z; s.w += p.w;
  }
  aout[i+0]=f2b(s.x); aout[i+1]=f2b(s.y); aout[i+2]=f2b(s.z); aout[i+3]=f2b(s.w);
}

// ---------------- out proj (MFMA): aout[2048,768] @ w_out^T + b_out -> f32 ----------------
__global__ __launch_bounds__(256) void gemm_out(const bf16* __restrict__ A,
                                                const bf16* __restrict__ W,
                                                const float* __restrict__ bias,
                                                float* __restrict__ out){
  __shared__ bf16 As[128*32];
  __shared__ bf16 Bs[128*32];
  int n0 = blockIdx.x*128, m0 = blockIdx.y*128;
  int t = threadIdx.x, w = t>>6, lane = t&63;
  int ln16 = lane&15, q8 = (lane>>4)*8;
  int wm = w>>1, wn = w&1;
  f32x4 acc[4][4] = {};
  for (int k0=0; k0<768; k0+=32){
    __syncthreads();
    #pragma unroll
    for (int i=0;i<2;i++){
      int cc = t + i*256;
      int r = cc>>2, ko = (cc&3)*8;
      gl_lds16(&A[(size_t)(m0+r)*768 + k0+ko], &As[(size_t)(w*64 + i*256)*8]);
      gl_lds16(&W[(size_t)(n0+r)*768 + k0+ko], &Bs[(size_t)(w*64 + i*256)*8]);
    }
    __syncthreads();
    short8 af[4], bfr[4];
    #pragma unroll
    for (int mi=0;mi<4;mi++) af[mi]  = *(const short8*)&As[(wm*64+mi*16+ln16)*32 + q8];
    #pragma unroll
    for (int ni=0;ni<4;ni++) bfr[ni] = *(const short8*)&Bs[(wn*64+ni*16+ln16)*32 + q8];
    #pragma unroll
    for (int mi=0;mi<4;mi++)
      #pragma unroll
      for (int ni=0;ni<4;ni++)
        acc[mi][ni] = __builtin_amdgcn_mfma_f32_16x16x32_bf16(af[mi], bfr[ni], acc[mi][ni], 0, 0, 0);
  }
  int quad4 = (lane>>4)*4;
  #pragma unroll
  for (int mi=0;mi<4;mi++)
    #pragma unroll
    for (int ni=0;ni<4;ni++){
      int cg = n0 + wn*64 + ni*16 + ln16;
      #pragma unroll
      for (int r=0;r<4;r++){
        int m = m0 + wm*64 + mi*16 + quad4 + r;
        out[(size_t)m*768 + cg] = acc[mi][ni][r] + bias[cg];
      }
    }
}

extern "C" void kernel_launch(void* const* d_in, const int* in_sizes, int n_in,
                              void* d_out, int out_size, void* d_ws, size_t ws_size,
                              hipStream_t stream){
  const float* x     = (const float*)d_in[0];
  const float* ln_g  = (const float*)d_in[1];
  const float* ln_b  = (const float*)d_in[2];
  const float* w_qkv = (const float*)d_in[3];
  const float* w_out = (const float*)d_in[4];
  const float* b_out = (const float*)d_in[5];
  const float* theta = (const float*)d_in[6];
  const float* gnn   = (const float*)d_in[7];
  float* out = (float*)d_out;

  char* p = (char*)d_ws;
  bf16* xnb   = (bf16*)p; p += (size_t)2048*768*2;
  bf16* wqkvb = (bf16*)p; p += (size_t)2304*768*2;
  bf16* woutb = (bf16*)p; p += (size_t)768*768*2;   // contiguous after wqkvb
  bf16* qb    = (bf16*)p; p += (size_t)NB*NH*SEQ*DH*2;
  bf16* kb    = (bf16*)p; p += (size_t)NB*NH*SEQ*DH*2;
  bf16* vtb   = (bf16*)p; p += (size_t)NB*NH*SEQ*DH*2;
  bf16* aoutb = (bf16*)p; p += (size_t)2048*768*2;
  float* Mm   = (float*)p; p += 256*4;
  float* lsum = (float*)p; p += (size_t)NB*NH*SEQ*4;
  bf16* expg  = (bf16*)p; p += (size_t)NB*NH*SEQ*SEQ*2;   // 50.3 MB
  float* opart= (float*)p;                                // NCHM*2048*768 f32 = 50.3 MB

  const int N1 = 2304*768, N2 = 768*768;
  prep_all<<<dim3(2048+9216+97), dim3(256), 0, stream>>>(
      x, ln_g, ln_b, w_qkv, N1, w_out, N2, theta, gnn, xnb, wqkvb, Mm, lsum);
  gemm_qkv<<<dim3(18, 16), dim3(256), 0, stream>>>(xnb, wqkvb, qb, kb, vtb);
  attn_exp<<<dim3(64, NCHE, NB*3), dim3(256), 0, stream>>>(qb, kb, lsum, expg);
  attn_main<<<dim3(64, NCHM, NB), dim3(768), 0, stream>>>(expg, vtb, Mm, lsum, opart);
  reduce_kernel<<<dim3((NB*SEQ*DMODEL/4+255)/256), dim3(256), 0, stream>>>(opart, aoutb);
  gemm_out<<<dim3(6, 16), dim3(256), 0, stream>>>(aoutb, woutb, b_out, out);
}

// Round 12
// 246.141 us; speedup vs baseline: 1.0774x; 1.0774x over previous
//
#include <hip/hip_runtime.h>
#include <hip/hip_bf16.h>
#include <stdint.h>

#define NB 2
#define SEQ 1024
#define DMODEL 768
#define NH 12
#define DH 64
#define SCALE 0.125f
#define NCH 4          // column chunks in fused attention

typedef __hip_bfloat16 bf16;
typedef __attribute__((ext_vector_type(8))) short short8;   // 8 x bf16 = 4 VGPRs
typedef __attribute__((ext_vector_type(4))) float f32x4;    // MFMA C/D

__device__ __forceinline__ bf16 f2b(float x){ return __float2bfloat16(x); }
__device__ __forceinline__ short f2bs(float x){
  bf16 h = __float2bfloat16(x); return *reinterpret_cast<short*>(&h);
}
__device__ __forceinline__ float s2f(short u){
  return __uint_as_float(((unsigned)(unsigned short)u) << 16);
}

// async global->LDS 16B: LDS dest wave-uniform base; HW adds lane*16.
__device__ __forceinline__ void gl_lds16(const bf16* g, bf16* l){
  __builtin_amdgcn_global_load_lds(
      (const __attribute__((address_space(1))) void*)g,
      (__attribute__((address_space(3))) void*)l, 16, 0, 0);
}

// ---------------- merged prelude: LN rows | weight cvt | M + lsum zero ----------------
__global__ __launch_bounds__(256) void prep_all(const float* __restrict__ x,
                                                const float* __restrict__ g,
                                                const float* __restrict__ bta,
                                                const float* __restrict__ w1, int n1,
                                                const float* __restrict__ w2, int n2,
                                                const float* __restrict__ theta,
                                                const float* __restrict__ gnn,
                                                bf16* __restrict__ xn,
                                                bf16* __restrict__ wb,
                                                float* __restrict__ Mm,
                                                float* __restrict__ l){
  int bx = blockIdx.x, t = threadIdx.x;
  if (bx < 2048){
    const float* xr = x + (size_t)bx*DMODEL;
    float v0[3]; float s = 0.f, s2 = 0.f;
    #pragma unroll
    for (int i=0;i<3;i++){ float val = xr[t+256*i]; v0[i]=val; s+=val; s2+=val*val; }
    __shared__ float sb[256], s2b[256];
    sb[t]=s; s2b[t]=s2; __syncthreads();
    for (int off=128; off>0; off>>=1){
      if (t<off){ sb[t]+=sb[t+off]; s2b[t]+=s2b[t+off]; }
      __syncthreads();
    }
    float mean = sb[0]*(1.f/DMODEL);
    float var  = s2b[0]*(1.f/DMODEL) - mean*mean;
    float rstd = rsqrtf(var + 1e-5f);
    #pragma unroll
    for (int i=0;i<3;i++){
      int c = t+256*i;
      xn[(size_t)bx*DMODEL + c] = f2b((v0[i]-mean)*rstd*g[c] + bta[c]);
    }
  } else if (bx < 2048+9216){
    int i = (bx-2048)*256 + t;
    if (i < n1) wb[i] = f2b(w1[i]);
    else if (i < n1+n2) wb[i] = f2b(w2[i-n1]);
  } else {
    int sub = bx - (2048+9216);
    if (sub == 0){
      if (t < 144){
        int i = t/12, kx = t%12;
        float sacc = 0.f;
        for (int j=0;j<12;j++) sacc += (-0.5f)*theta[i*12+j] * gnn[j*12+kx];
        Mm[t] = sacc;
      }
    } else {
      l[(sub-1)*256 + t] = 0.f;    // 96*256 = 24576 = 2*12*1024
    }
  }
}

// ---------------- QKV GEMM (MFMA): xn[2048,768] @ wqkv^T -> q,k bf16 [b,h,n,d]; v -> vt [b,h,d,n] ----------------
__global__ __launch_bounds__(256) void gemm_qkv(const bf16* __restrict__ A,
                                                const bf16* __restrict__ W,
                                                bf16* __restrict__ q,
                                                bf16* __restrict__ k,
                                                bf16* __restrict__ vt){
  __shared__ bf16 As[128*32];
  __shared__ bf16 Bs[128*32];
  int n0 = blockIdx.x*128, m0 = blockIdx.y*128;
  int t = threadIdx.x, w = t>>6, lane = t&63;
  int ln16 = lane&15, q8 = (lane>>4)*8;
  int wm = w>>1, wn = w&1;
  f32x4 acc[4][4] = {};
  for (int k0=0; k0<768; k0+=32){
    __syncthreads();
    #pragma unroll
    for (int i=0;i<2;i++){
      int cc = t + i*256;
      int r = cc>>2, ko = (cc&3)*8;
      gl_lds16(&A[(size_t)(m0+r)*768 + k0+ko], &As[(size_t)(w*64 + i*256)*8]);
      gl_lds16(&W[(size_t)(n0+r)*768 + k0+ko], &Bs[(size_t)(w*64 + i*256)*8]);
    }
    __syncthreads();
    short8 af[4], bfr[4];
    #pragma unroll
    for (int mi=0;mi<4;mi++) af[mi]  = *(const short8*)&As[(wm*64+mi*16+ln16)*32 + q8];
    #pragma unroll
    for (int ni=0;ni<4;ni++) bfr[ni] = *(const short8*)&Bs[(wn*64+ni*16+ln16)*32 + q8];
    #pragma unroll
    for (int mi=0;mi<4;mi++)
      #pragma unroll
      for (int ni=0;ni<4;ni++)
        acc[mi][ni] = __builtin_amdgcn_mfma_f32_16x16x32_bf16(af[mi], bfr[ni], acc[mi][ni], 0, 0, 0);
  }
  int quad4 = (lane>>4)*4;
  #pragma unroll
  for (int mi=0;mi<4;mi++){
    #pragma unroll
    for (int ni=0;ni<4;ni++){
      int cg = n0 + wn*64 + ni*16 + ln16;
      int which = cg/768; int rem = cg - which*768;
      int h = rem>>6, dd = rem&63;
      #pragma unroll
      for (int r=0;r<4;r++){
        int m = m0 + wm*64 + mi*16 + quad4 + r;
        int bb = m>>10, n = m&1023;
        float val = acc[mi][ni][r];
        if (which==0)      q [((size_t)(bb*NH+h)*SEQ + n)*DH + dd] = f2b(val*SCALE);
        else if (which==1) k [((size_t)(bb*NH+h)*SEQ + n)*DH + dd] = f2b(val);
        else               vt[((size_t)(bb*NH+h)*DH + dd)*SEQ + n] = f2b(val);
      }
    }
  }
}

// ---------------- pass 1 (col-chunked): l[b,h,n] += sum_chunk exp(s) ----------------
__global__ __launch_bounds__(768) void attn_sums(const bf16* __restrict__ q,
                                                 const bf16* __restrict__ k,
                                                 float* __restrict__ l){
  int b = blockIdx.z, ch = blockIdx.y; int r0 = blockIdx.x*16;
  int t = threadIdx.x; int h = t>>6; int lane = t&63;
  int ln16 = lane&15, quad = lane>>4; int q8 = quad*8, quad4 = quad*4;
  const bf16* qrow = q + ((size_t)(b*NH+h)*SEQ + r0 + ln16)*DH;
  short8 aq0 = *(const short8*)(qrow + q8);
  short8 aq1 = *(const short8*)(qrow + 32 + q8);
  const bf16* kB = k + ((size_t)(b*NH+h)*SEQ)*DH;
  float ls[4] = {0.f,0.f,0.f,0.f};
  #pragma unroll 4
  for (int i=0;i<16;i++){
    int c0 = ch*256 + i*16;
    const bf16* krow = kB + (size_t)(c0 + ln16)*DH;
    short8 bk0 = *(const short8*)(krow + q8);
    short8 bk1 = *(const short8*)(krow + 32 + q8);
    f32x4 a = {0.f,0.f,0.f,0.f};
    a = __builtin_amdgcn_mfma_f32_16x16x32_bf16(aq0, bk0, a, 0, 0, 0);
    a = __builtin_amdgcn_mfma_f32_16x16x32_bf16(aq1, bk1, a, 0, 0, 0);
    #pragma unroll
    for (int r=0;r<4;r++) ls[r] += __expf(a[r]);
  }
  #pragma unroll
  for (int msk=1; msk<16; msk<<=1){
    #pragma unroll
    for (int r=0;r<4;r++) ls[r] += __shfl_xor(ls[r], msk);
  }
  if (ln16 == 0){
    #pragma unroll
    for (int r=0;r<4;r++)
      atomicAdd(&l[((size_t)(b*NH+h))*SEQ + r0 + quad4 + r], ls[r]);
  }
}

// ---------------- pass 2 (col-chunked): scores->softmax->mix(in-reg)->PV partial (bf16) ----------------
// r8's proven kernel (56 us); only the epilogue dtype changed (bf16 partials, reduce
// folded into gemm_out's K loop).
__global__ __launch_bounds__(768) void attn_main(const bf16* __restrict__ q,
                                                 const bf16* __restrict__ k,
                                                 const bf16* __restrict__ vt,
                                                 const float* __restrict__ Mm,
                                                 const float* __restrict__ l,
                                                 bf16* __restrict__ opart){
  __shared__ bf16 attT[2][NH][16][40];     // 30720 B
  __shared__ float Ms[144];
  int b = blockIdx.z, ch = blockIdx.y; int r0 = blockIdx.x*16;
  int t = threadIdx.x; int h = t>>6; int lane = t&63;
  int ln16 = lane&15, quad = lane>>4; int q8 = quad*8, quad4 = quad*4;
  const bf16* kB = k  + ((size_t)(b*NH+h)*SEQ)*DH;
  const bf16* vB = vt + ((size_t)(b*NH+h)*DH)*SEQ;

  if (t < 144) Ms[t] = Mm[t];              // covered by iteration-0 barrier

  const bf16* qrow = q + ((size_t)(b*NH+h)*SEQ + r0 + ln16)*DH;
  short8 aq0 = *(const short8*)(qrow + q8);
  short8 aq1 = *(const short8*)(qrow + 32 + q8);

  float inv_l[4];
  #pragma unroll
  for (int r=0;r<4;r++) inv_l[r] = 1.0f / l[((size_t)(b*NH+h))*SEQ + r0 + quad4 + r];

  f32x4 oacc[4] = {};
  for (int it=0; it<8; it++){
    int c0 = ch*256 + it*32;
    int buf = it&1;
    // phase A: normalized attn tile -> attT[buf][h][row][col]
    #pragma unroll
    for (int half=0; half<2; half++){
      const bf16* krow = kB + (size_t)(c0 + half*16 + ln16)*DH;
      short8 bk0 = *(const short8*)(krow + q8);
      short8 bk1 = *(const short8*)(krow + 32 + q8);
      f32x4 a = {0.f,0.f,0.f,0.f};
      a = __builtin_amdgcn_mfma_f32_16x16x32_bf16(aq0, bk0, a, 0, 0, 0);
      a = __builtin_amdgcn_mfma_f32_16x16x32_bf16(aq1, bk1, a, 0, 0, 0);
      #pragma unroll
      for (int r=0;r<4;r++)
        attT[buf][h][quad4+r][half*16 + ln16] = f2b(__expf(a[r])*inv_l[r]);
    }
    __syncthreads();
    // phase B: in-register head mix -> PV A-frag
    float sm[8] = {0.f,0.f,0.f,0.f,0.f,0.f,0.f,0.f};
    #pragma unroll
    for (int j=0;j<12;j++){
      short8 u = *(const short8*)&attT[buf][j][ln16][q8];
      float m = Ms[h*12+j];
      #pragma unroll
      for (int e=0;e<8;e++) sm[e] += m*s2f(u[e]);
    }
    short8 uh = *(const short8*)&attT[buf][h][ln16][q8];
    short8 afrag;
    #pragma unroll
    for (int e=0;e<8;e++) afrag[e] = f2bs(s2f(uh[e]) + fmaxf(sm[e], 0.f));
    // phase C: O += comb @ V
    #pragma unroll
    for (int ni=0; ni<4; ni++){
      short8 bv = *(const short8*)&vB[(size_t)(ni*16 + ln16)*SEQ + c0 + q8];
      oacc[ni] = __builtin_amdgcn_mfma_f32_16x16x32_bf16(afrag, bv, oacc[ni], 0, 0, 0);
    }
  }
  // epilogue: bf16 partial O for this chunk
  bf16* dst = opart + ((size_t)ch*NB*SEQ + (size_t)b*SEQ)*DMODEL;
  #pragma unroll
  for (int ni=0; ni<4; ni++)
    #pragma unroll
    for (int r=0; r<4; r++){
      int n = r0 + quad4 + r;
      dst[(size_t)n*DMODEL + h*DH + ni*16 + ln16] = f2b(oacc[ni][r]);
    }
}

// ---------------- out proj (MFMA), K=3072: out = (sum_ch opart_ch) @ w_out^T + b_out ----------------
// K loop runs over 4 chunks x 768; each 32-wide K tile lies within one chunk.
__global__ __launch_bounds__(256) void gemm_out(const bf16* __restrict__ opart,
                                                const bf16* __restrict__ W,
                                                const float* __restrict__ bias,
                                                float* __restrict__ out){
  __shared__ bf16 As[128*32];
  __shared__ bf16 Bs[128*32];
  int n0 = blockIdx.x*128, m0 = blockIdx.y*128;
  int t = threadIdx.x, w = t>>6, lane = t&63;
  int ln16 = lane&15, q8 = (lane>>4)*8;
  int wm = w>>1, wn = w&1;
  f32x4 acc[4][4] = {};
  for (int k0=0; k0<NCH*768; k0+=32){
    int ch = k0/768, kk0 = k0 - ch*768;
    const bf16* Aب = opart + (size_t)ch*NB*SEQ*DMODEL;
    __syncthreads();
    #pragma unroll
    for (int i=0;i<2;i++){
      int cc = t + i*256;
      int r = cc>>2, ko = (cc&3)*8;
      gl_lds16(&Aب[(size_t)(m0+r)*768 + kk0+ko], &As[(size_t)(w*64 + i*256)*8]);
      gl_lds16(&W[(size_t)(n0+r)*768 + kk0+ko], &Bs[(size_t)(w*64 + i*256)*8]);
    }
    __syncthreads();
    short8 af[4], bfr[4];
    #pragma unroll
    for (int mi=0;mi<4;mi++) af[mi]  = *(const short8*)&As[(wm*64+mi*16+ln16)*32 + q8];
    #pragma unroll
    for (int ni=0;ni<4;ni++) bfr[ni] = *(const short8*)&Bs[(wn*64+ni*16+ln16)*32 + q8];
    #pragma unroll
    for (int mi=0;mi<4;mi++)
      #pragma unroll
      for (int ni=0;ni<4;ni++)
        acc[mi][ni] = __builtin_amdgcn_mfma_f32_16x16x32_bf16(af[mi], bfr[ni], acc[mi][ni], 0, 0, 0);
  }
  int quad4 = (lane>>4)*4;
  #pragma unroll
  for (int mi=0;mi<4;mi++)
    #pragma unroll
    for (int ni=0;ni<4;ni++){
      int cg = n0 + wn*64 + ni*16 + ln16;
      #pragma unroll
      for (int r=0;r<4;r++){
        int m = m0 + wm*64 + mi*16 + quad4 + r;
        out[(size_t)m*768 + cg] = acc[mi][ni][r] + bias[cg];
      }
    }
}

extern "C" void kernel_launch(void* const* d_in, const int* in_sizes, int n_in,
                              void* d_out, int out_size, void* d_ws, size_t ws_size,
                              hipStream_t stream){
  const float* x     = (const float*)d_in[0];
  const float* ln_g  = (const float*)d_in[1];
  const float* ln_b  = (const float*)d_in[2];
  const float* w_qkv = (const float*)d_in[3];
  const float* w_out = (const float*)d_in[4];
  const float* b_out = (const float*)d_in[5];
  const float* theta = (const float*)d_in[6];
  const float* gnn   = (const float*)d_in[7];
  float* out = (float*)d_out;

  char* p = (char*)d_ws;
  bf16* xnb   = (bf16*)p; p += (size_t)2048*768*2;
  bf16* wqkvb = (bf16*)p; p += (size_t)2304*768*2;
  bf16* woutb = (bf16*)p; p += (size_t)768*768*2;   // contiguous after wqkvb
  bf16* qb    = (bf16*)p; p += (size_t)NB*NH*SEQ*DH*2;
  bf16* kb    = (bf16*)p; p += (size_t)NB*NH*SEQ*DH*2;
  bf16* vtb   = (bf16*)p; p += (size_t)NB*NH*SEQ*DH*2;
  float* Mm   = (float*)p; p += 256*4;
  float* lsum = (float*)p; p += (size_t)NB*NH*SEQ*4;
  bf16* opart = (bf16*)p;                           // NCH * 2048*768 bf16 = 25.2 MB

  const int N1 = 2304*768, N2 = 768*768;
  prep_all<<<dim3(2048+9216+97), dim3(256), 0, stream>>>(
      x, ln_g, ln_b, w_qkv, N1, w_out, N2, theta, gnn, xnb, wqkvb, Mm, lsum);
  gemm_qkv<<<dim3(18, 16), dim3(256), 0, stream>>>(xnb, wqkvb, qb, kb, vtb);
  attn_sums<<<dim3(64, NCH, NB), dim3(768), 0, stream>>>(qb, kb, lsum);
  attn_main<<<dim3(64, NCH, NB), dim3(768), 0, stream>>>(qb, kb, vtb, Mm, lsum, opart);
  gemm_out<<<dim3(6, 16), dim3(256), 0, stream>>>(opart, woutb, b_out, out);
}

// Round 13
// 198.699 us; speedup vs baseline: 1.3346x; 1.2388x over previous
//
#include <hip/hip_runtime.h>
#include <hip/hip_bf16.h>
#include <stdint.h>

#define NB 2
#define SEQ 1024
#define DMODEL 768
#define NH 12
#define DH 64
#define SCALE 0.125f
#define NCH 4          // column chunks in fused attention

typedef __hip_bfloat16 bf16;
typedef __attribute__((ext_vector_type(8))) short short8;   // 8 x bf16 = 4 VGPRs
typedef __attribute__((ext_vector_type(4))) float f32x4;    // MFMA C/D

__device__ __forceinline__ bf16 f2b(float x){ return __float2bfloat16(x); }
__device__ __forceinline__ short f2bs(float x){
  bf16 h = __float2bfloat16(x); return *reinterpret_cast<short*>(&h);
}
__device__ __forceinline__ float s2f(short u){
  return __uint_as_float(((unsigned)(unsigned short)u) << 16);
}

// async global->LDS 16B: LDS dest wave-uniform base; HW adds lane*16.
__device__ __forceinline__ void gl_lds16(const bf16* g, bf16* l){
  __builtin_amdgcn_global_load_lds(
      (const __attribute__((address_space(1))) void*)g,
      (__attribute__((address_space(3))) void*)l, 16, 0, 0);
}

// ---------------- merged prelude: LN rows | weight cvt | M + lsum zero ----------------
__global__ __launch_bounds__(256) void prep_all(const float* __restrict__ x,
                                                const float* __restrict__ g,
                                                const float* __restrict__ bta,
                                                const float* __restrict__ w1, int n1,
                                                const float* __restrict__ w2, int n2,
                                                const float* __restrict__ theta,
                                                const float* __restrict__ gnn,
                                                bf16* __restrict__ xn,
                                                bf16* __restrict__ wb,
                                                float* __restrict__ Mm,
                                                float* __restrict__ l){
  int bx = blockIdx.x, t = threadIdx.x;
  if (bx < 2048){
    const float* xr = x + (size_t)bx*DMODEL;
    float v0[3]; float s = 0.f, s2 = 0.f;
    #pragma unroll
    for (int i=0;i<3;i++){ float val = xr[t+256*i]; v0[i]=val; s+=val; s2+=val*val; }
    __shared__ float sb[256], s2b[256];
    sb[t]=s; s2b[t]=s2; __syncthreads();
    for (int off=128; off>0; off>>=1){
      if (t<off){ sb[t]+=sb[t+off]; s2b[t]+=s2b[t+off]; }
      __syncthreads();
    }
    float mean = sb[0]*(1.f/DMODEL);
    float var  = s2b[0]*(1.f/DMODEL) - mean*mean;
    float rstd = rsqrtf(var + 1e-5f);
    #pragma unroll
    for (int i=0;i<3;i++){
      int c = t+256*i;
      xn[(size_t)bx*DMODEL + c] = f2b((v0[i]-mean)*rstd*g[c] + bta[c]);
    }
  } else if (bx < 2048+9216){
    int i = (bx-2048)*256 + t;
    if (i < n1) wb[i] = f2b(w1[i]);
    else if (i < n1+n2) wb[i] = f2b(w2[i-n1]);
  } else {
    int sub = bx - (2048+9216);
    if (sub == 0){
      if (t < 144){
        int i = t/12, kx = t%12;
        float sacc = 0.f;
        for (int j=0;j<12;j++) sacc += (-0.5f)*theta[i*12+j] * gnn[j*12+kx];
        Mm[t] = sacc;
      }
    } else {
      l[(sub-1)*256 + t] = 0.f;    // 96*256 = 24576 = 2*12*1024
    }
  }
}

// ---------------- QKV GEMM (MFMA): xn[2048,768] @ wqkv^T -> q,k bf16 [b,h,n,d]; v -> vt [b,h,d,n] ----------------
__global__ __launch_bounds__(256) void gemm_qkv(const bf16* __restrict__ A,
                                                const bf16* __restrict__ W,
                                                bf16* __restrict__ q,
                                                bf16* __restrict__ k,
                                                bf16* __restrict__ vt){
  __shared__ bf16 As[128*32];
  __shared__ bf16 Bs[128*32];
  int n0 = blockIdx.x*128, m0 = blockIdx.y*128;
  int t = threadIdx.x, w = t>>6, lane = t&63;
  int ln16 = lane&15, q8 = (lane>>4)*8;
  int wm = w>>1, wn = w&1;
  f32x4 acc[4][4] = {};
  for (int k0=0; k0<768; k0+=32){
    __syncthreads();
    #pragma unroll
    for (int i=0;i<2;i++){
      int cc = t + i*256;
      int r = cc>>2, ko = (cc&3)*8;
      gl_lds16(&A[(size_t)(m0+r)*768 + k0+ko], &As[(size_t)(w*64 + i*256)*8]);
      gl_lds16(&W[(size_t)(n0+r)*768 + k0+ko], &Bs[(size_t)(w*64 + i*256)*8]);
    }
    __syncthreads();
    short8 af[4], bfr[4];
    #pragma unroll
    for (int mi=0;mi<4;mi++) af[mi]  = *(const short8*)&As[(wm*64+mi*16+ln16)*32 + q8];
    #pragma unroll
    for (int ni=0;ni<4;ni++) bfr[ni] = *(const short8*)&Bs[(wn*64+ni*16+ln16)*32 + q8];
    #pragma unroll
    for (int mi=0;mi<4;mi++)
      #pragma unroll
      for (int ni=0;ni<4;ni++)
        acc[mi][ni] = __builtin_amdgcn_mfma_f32_16x16x32_bf16(af[mi], bfr[ni], acc[mi][ni], 0, 0, 0);
  }
  int quad4 = (lane>>4)*4;
  #pragma unroll
  for (int mi=0;mi<4;mi++){
    #pragma unroll
    for (int ni=0;ni<4;ni++){
      int cg = n0 + wn*64 + ni*16 + ln16;
      int which = cg/768; int rem = cg - which*768;
      int h = rem>>6, dd = rem&63;
      #pragma unroll
      for (int r=0;r<4;r++){
        int m = m0 + wm*64 + mi*16 + quad4 + r;
        int bb = m>>10, n = m&1023;
        float val = acc[mi][ni][r];
        if (which==0)      q [((size_t)(bb*NH+h)*SEQ + n)*DH + dd] = f2b(val*SCALE);
        else if (which==1) k [((size_t)(bb*NH+h)*SEQ + n)*DH + dd] = f2b(val);
        else               vt[((size_t)(bb*NH+h)*DH + dd)*SEQ + n] = f2b(val);
      }
    }
  }
}

// ---------------- pass 1 (col-chunked): l[b,h,n] += sum_chunk exp(s) ----------------
__global__ __launch_bounds__(768) void attn_sums(const bf16* __restrict__ q,
                                                 const bf16* __restrict__ k,
                                                 float* __restrict__ l){
  int b = blockIdx.z, ch = blockIdx.y; int r0 = blockIdx.x*16;
  int t = threadIdx.x; int h = t>>6; int lane = t&63;
  int ln16 = lane&15, quad = lane>>4; int q8 = quad*8, quad4 = quad*4;
  const bf16* qrow = q + ((size_t)(b*NH+h)*SEQ + r0 + ln16)*DH;
  short8 aq0 = *(const short8*)(qrow + q8);
  short8 aq1 = *(const short8*)(qrow + 32 + q8);
  const bf16* kB = k + ((size_t)(b*NH+h)*SEQ)*DH;
  float ls[4] = {0.f,0.f,0.f,0.f};
  #pragma unroll 4
  for (int i=0;i<16;i++){
    int c0 = ch*256 + i*16;
    const bf16* krow = kB + (size_t)(c0 + ln16)*DH;
    short8 bk0 = *(const short8*)(krow + q8);
    short8 bk1 = *(const short8*)(krow + 32 + q8);
    f32x4 a = {0.f,0.f,0.f,0.f};
    a = __builtin_amdgcn_mfma_f32_16x16x32_bf16(aq0, bk0, a, 0, 0, 0);
    a = __builtin_amdgcn_mfma_f32_16x16x32_bf16(aq1, bk1, a, 0, 0, 0);
    #pragma unroll
    for (int r=0;r<4;r++) ls[r] += __expf(a[r]);
  }
  #pragma unroll
  for (int msk=1; msk<16; msk<<=1){
    #pragma unroll
    for (int r=0;r<4;r++) ls[r] += __shfl_xor(ls[r], msk);
  }
  if (ln16 == 0){
    #pragma unroll
    for (int r=0;r<4;r++)
      atomicAdd(&l[((size_t)(b*NH+h))*SEQ + r0 + quad4 + r], ls[r]);
  }
}

// ---------------- pass 2 (col-chunked): scores->softmax->mix(in-reg)->PV partial (bf16) ----------------
__global__ __launch_bounds__(768) void attn_main(const bf16* __restrict__ q,
                                                 const bf16* __restrict__ k,
                                                 const bf16* __restrict__ vt,
                                                 const float* __restrict__ Mm,
                                                 const float* __restrict__ l,
                                                 bf16* __restrict__ opart){
  __shared__ bf16 attT[2][NH][16][40];     // 30720 B
  __shared__ float Ms[144];
  int b = blockIdx.z, ch = blockIdx.y; int r0 = blockIdx.x*16;
  int t = threadIdx.x; int h = t>>6; int lane = t&63;
  int ln16 = lane&15, quad = lane>>4; int q8 = quad*8, quad4 = quad*4;
  const bf16* kB = k  + ((size_t)(b*NH+h)*SEQ)*DH;
  const bf16* vB = vt + ((size_t)(b*NH+h)*DH)*SEQ;

  if (t < 144) Ms[t] = Mm[t];              // covered by iteration-0 barrier

  const bf16* qrow = q + ((size_t)(b*NH+h)*SEQ + r0 + ln16)*DH;
  short8 aq0 = *(const short8*)(qrow + q8);
  short8 aq1 = *(const short8*)(qrow + 32 + q8);

  float inv_l[4];
  #pragma unroll
  for (int r=0;r<4;r++) inv_l[r] = 1.0f / l[((size_t)(b*NH+h))*SEQ + r0 + quad4 + r];

  f32x4 oacc[4] = {};
  for (int it=0; it<8; it++){
    int c0 = ch*256 + it*32;
    int buf = it&1;
    // phase A: normalized attn tile -> attT[buf][h][row][col]
    #pragma unroll
    for (int half=0; half<2; half++){
      const bf16* krow = kB + (size_t)(c0 + half*16 + ln16)*DH;
      short8 bk0 = *(const short8*)(krow + q8);
      short8 bk1 = *(const short8*)(krow + 32 + q8);
      f32x4 a = {0.f,0.f,0.f,0.f};
      a = __builtin_amdgcn_mfma_f32_16x16x32_bf16(aq0, bk0, a, 0, 0, 0);
      a = __builtin_amdgcn_mfma_f32_16x16x32_bf16(aq1, bk1, a, 0, 0, 0);
      #pragma unroll
      for (int r=0;r<4;r++)
        attT[buf][h][quad4+r][half*16 + ln16] = f2b(__expf(a[r])*inv_l[r]);
    }
    __syncthreads();
    // phase B: in-register head mix -> PV A-frag
    float sm[8] = {0.f,0.f,0.f,0.f,0.f,0.f,0.f,0.f};
    #pragma unroll
    for (int j=0;j<12;j++){
      short8 u = *(const short8*)&attT[buf][j][ln16][q8];
      float m = Ms[h*12+j];
      #pragma unroll
      for (int e=0;e<8;e++) sm[e] += m*s2f(u[e]);
    }
    short8 uh = *(const short8*)&attT[buf][h][ln16][q8];
    short8 afrag;
    #pragma unroll
    for (int e=0;e<8;e++) afrag[e] = f2bs(s2f(uh[e]) + fmaxf(sm[e], 0.f));
    // phase C: O += comb @ V
    #pragma unroll
    for (int ni=0; ni<4; ni++){
      short8 bv = *(const short8*)&vB[(size_t)(ni*16 + ln16)*SEQ + c0 + q8];
      oacc[ni] = __builtin_amdgcn_mfma_f32_16x16x32_bf16(afrag, bv, oacc[ni], 0, 0, 0);
    }
  }
  // epilogue: bf16 partial O for this chunk
  bf16* dst = opart + ((size_t)ch*NB*SEQ + (size_t)b*SEQ)*DMODEL;
  #pragma unroll
  for (int ni=0; ni<4; ni++)
    #pragma unroll
    for (int r=0; r<4; r++){
      int n = r0 + quad4 + r;
      dst[(size_t)n*DMODEL + h*DH + ni*16 + ln16] = f2b(oacc[ni][r]);
    }
}

// ---------------- reduce partials (bf16): aout = bf16( sum_ch opart ) ----------------
__global__ __launch_bounds__(256) void reduce_kernel(const bf16* __restrict__ opart,
                                                     bf16* __restrict__ aout){
  const size_t TOT = (size_t)NB*SEQ*DMODEL;      // 1,572,864
  size_t i = ((size_t)blockIdx.x*256 + threadIdx.x)*8;
  float s[8] = {};
  #pragma unroll
  for (int c=0;c<NCH;c++){
    short8 u = *(const short8*)&opart[c*TOT + i];
    #pragma unroll
    for (int e=0;e<8;e++) s[e] += s2f(u[e]);
  }
  short8 o;
  #pragma unroll
  for (int e=0;e<8;e++) o[e] = f2bs(s[e]);
  *(short8*)&aout[i] = o;
}

// ---------------- out proj (MFMA, 64x64 tiles): aout[2048,768] @ w_out^T + b_out -> f32 ----------------
// grid (12,32)=384 blocks (vs 96 at 128-tile: was 4% occupancy, latency-bound).
__global__ __launch_bounds__(256) void gemm_out(const bf16* __restrict__ A,
                                                const bf16* __restrict__ W,
                                                const float* __restrict__ bias,
                                                float* __restrict__ out){
  __shared__ bf16 As[64*32];
  __shared__ bf16 Bs[64*32];
  int n0 = blockIdx.x*64, m0 = blockIdx.y*64;
  int t = threadIdx.x, w = t>>6, lane = t&63;
  int ln16 = lane&15, q8 = (lane>>4)*8;
  int wm = w>>1, wn = w&1;
  f32x4 acc[2][2] = {};
  for (int k0=0; k0<768; k0+=32){
    __syncthreads();
    {
      int r = t>>2, ko = (t&3)*8;
      gl_lds16(&A[(size_t)(m0+r)*768 + k0+ko], &As[(size_t)(w*64)*8]);
      gl_lds16(&W[(size_t)(n0+r)*768 + k0+ko], &Bs[(size_t)(w*64)*8]);
    }
    __syncthreads();
    short8 af[2], bfr[2];
    #pragma unroll
    for (int mi=0;mi<2;mi++) af[mi]  = *(const short8*)&As[(wm*32+mi*16+ln16)*32 + q8];
    #pragma unroll
    for (int ni=0;ni<2;ni++) bfr[ni] = *(const short8*)&Bs[(wn*32+ni*16+ln16)*32 + q8];
    #pragma unroll
    for (int mi=0;mi<2;mi++)
      #pragma unroll
      for (int ni=0;ni<2;ni++)
        acc[mi][ni] = __builtin_amdgcn_mfma_f32_16x16x32_bf16(af[mi], bfr[ni], acc[mi][ni], 0, 0, 0);
  }
  int quad4 = (lane>>4)*4;
  #pragma unroll
  for (int mi=0;mi<2;mi++)
    #pragma unroll
    for (int ni=0;ni<2;ni++){
      int cg = n0 + wn*32 + ni*16 + ln16;
      #pragma unroll
      for (int r=0;r<4;r++){
        int m = m0 + wm*32 + mi*16 + quad4 + r;
        out[(size_t)m*768 + cg] = acc[mi][ni][r] + bias[cg];
      }
    }
}

extern "C" void kernel_launch(void* const* d_in, const int* in_sizes, int n_in,
                              void* d_out, int out_size, void* d_ws, size_t ws_size,
                              hipStream_t stream){
  const float* x     = (const float*)d_in[0];
  const float* ln_g  = (const float*)d_in[1];
  const float* ln_b  = (const float*)d_in[2];
  const float* w_qkv = (const float*)d_in[3];
  const float* w_out = (const float*)d_in[4];
  const float* b_out = (const float*)d_in[5];
  const float* theta = (const float*)d_in[6];
  const float* gnn   = (const float*)d_in[7];
  float* out = (float*)d_out;

  char* p = (char*)d_ws;
  bf16* xnb   = (bf16*)p; p += (size_t)2048*768*2;
  bf16* wqkvb = (bf16*)p; p += (size_t)2304*768*2;
  bf16* woutb = (bf16*)p; p += (size_t)768*768*2;   // contiguous after wqkvb
  bf16* qb    = (bf16*)p; p += (size_t)NB*NH*SEQ*DH*2;
  bf16* kb    = (bf16*)p; p += (size_t)NB*NH*SEQ*DH*2;
  bf16* vtb   = (bf16*)p; p += (size_t)NB*NH*SEQ*DH*2;
  bf16* aoutb = (bf16*)p; p += (size_t)2048*768*2;
  float* Mm   = (float*)p; p += 256*4;
  float* lsum = (float*)p; p += (size_t)NB*NH*SEQ*4;
  bf16* opart = (bf16*)p;                           // NCH * 2048*768 bf16 = 12.6 MB

  const int N1 = 2304*768, N2 = 768*768;
  prep_all<<<dim3(2048+9216+97), dim3(256), 0, stream>>>(
      x, ln_g, ln_b, w_qkv, N1, w_out, N2, theta, gnn, xnb, wqkvb, Mm, lsum);
  gemm_qkv<<<dim3(18, 16), dim3(256), 0, stream>>>(xnb, wqkvb, qb, kb, vtb);
  attn_sums<<<dim3(64, NCH, NB), dim3(768), 0, stream>>>(qb, kb, lsum);
  attn_main<<<dim3(64, NCH, NB), dim3(768), 0, stream>>>(qb, kb, vtb, Mm, lsum, opart);
  reduce_kernel<<<dim3(NB*SEQ*DMODEL/(8*256)), dim3(256), 0, stream>>>(opart, aoutb);
  gemm_out<<<dim3(12, 32), dim3(256), 0, stream>>>(aoutb, woutb, b_out, out);
}